// Round 7
// baseline (350.524 us; speedup 1.0000x reference)
//
#include <hip/hip_runtime.h>

#define SEQ_T 784
#define HID   128
#define S_H   160   // h-plane row stride in shorts (320B): rows land 2-per-bank-window
                    // on masked reads (free, m136); R12-verified (conflicts 1.19e5)

typedef __attribute__((ext_vector_type(8))) short  short8;
typedef __attribute__((ext_vector_type(4))) float  floatx4;
typedef __attribute__((ext_vector_type(8))) float  float8;

// bf16 round-to-nearest-even on raw bits (inputs finite)
static __device__ __forceinline__ short bf16_of(float f) {
  union { float f; unsigned u; } v; v.f = f;
  return (short)((v.u + 0x7fffu + ((v.u >> 16) & 1u)) >> 16);
}

#define MFMA_BF16 __builtin_amdgcn_mfma_f32_16x16x32_bf16

// 256 blocks x 4 batch rows (1 block/CU). R14 post-mortem: hybrid i8 cut MFMA
// pipe 400->265 cyc but dur ROSE 886->949 cyc/step -> the step is a serial
// LATENCY chain, not pipe-bound. Model: read-exposure ~120 + per-SIMD MFMA
// drain 466 (24 MFMA x 19.4 cyc/SIMD, 2 waves) + gate-VALU tail ~100 +
// write+barrier ~150 = ~850-900 ✓. R15 = R12-bf16 + chain surgery:
//  - exp2-direct gates, log2e folded INTO the bf16 Wh/Wi constants:
//    Wh_r,Wh_z scaled by -log2e (sigmoid arg comes out pre-negated/scaled),
//    Wh_n by +2log2e (tanh via 1-2/(1+exp2(t))) -> zero muls on the chain
//  - gate-major MFMA order (r x4, z x4, n x4, depth-1 chains + scalar tree):
//    r's dot exits the pipe at slot 4/12 -> sigmoids overlap the n-drain
//  - masked 2-way-free reads (R12), packed DPP+cvt_pk b32 write (R11), x2 unroll
extern "C" __global__ void __launch_bounds__(512, 2)
gru_lat_t(const float* __restrict__ x,    // [1024][784] fp32
          const float* __restrict__ Wi,   // [384]
          const float* __restrict__ bi,   // [384]
          const float* __restrict__ Wh,   // [384][128]
          const float* __restrict__ bh,   // [384]
          const float* __restrict__ Wfc,  // [10][128]
          const float* __restrict__ bfc,  // [10]
          float* __restrict__ out)        // [1024][10] fp32
{
  const int tid  = threadIdx.x;
  const int wv   = tid >> 6;
  const int lane = tid & 63;
  const int quad = lane >> 4;
  const int nn   = lane & 15;
  const int j    = (wv << 4) | nn;   // this lane's hidden column
  const int b0   = blockIdx.x * 4;   // 4 batch rows per block

  __shared__ __align__(16) float xs[SEQ_T][4];     // x fp32, [t][row]
  __shared__ __align__(16) short hb[2][4 * S_H];   // h bf16, 4 rows, dbuf
  __shared__ float hfin[4][HID];

  for (int i = tid; i < 2 * 4 * S_H; i += 512) ((short*)hb)[i] = 0;
  for (int i = tid; i < 4 * SEQ_T; i += 512) {
    const int r = i / SEQ_T;
    const int t = i - r * SEQ_T;
    xs[t][r] = x[(size_t)(b0 + r) * SEQ_T + t];
  }

  const float L2E  = 1.4426950408889634f;
  const float TL2E = 2.0f * L2E;

  // x-side constants, pre-scaled to match the weight scaling below:
  // sigmoid(p) = rcp(1 + exp2(arg)), arg = -L2E*p  (r,z)
  // tanh(q)    = 1 - 2*rcp(1 + exp2(t)), t = 2*L2E*q  (n)
  const float wi_rn = -Wi[j] * L2E;
  const float c_rn  = -(bi[j] + bh[j]) * L2E;
  const float wi_zn = -Wi[HID + j] * L2E;
  const float c_zn  = -(bi[HID + j] + bh[HID + j]) * L2E;
  const float win2  = Wi[2 * HID + j] * TL2E;
  const float bin2  = bi[2 * HID + j] * TL2E;
  const float bhn2  = bh[2 * HID + j] * TL2E;

  // Wh B-fragments, bf16, with the exp2 fold baked into the weights:
  // g=0 (r): -L2E*W, g=1 (z): -L2E*W, g=2 (n): +2*L2E*W.
  // Lane (quad,nn): B[k = kk*32 + quad*8 + e][n = nn] = scale*Wh[g*HID+j][k]
  short8 whi[3][4];
  #pragma unroll
  for (int g = 0; g < 3; ++g) {
    const float sc = (g == 2) ? TL2E : -L2E;
    const float* wrow = Wh + (size_t)(g * HID + j) * HID;
    #pragma unroll
    for (int kk = 0; kk < 4; ++kk) {
      float8 w = *(const float8*)(wrow + kk * 32 + quad * 8);
      short8 hi;
      #pragma unroll
      for (int e = 0; e < 8; ++e) hi[e] = bf16_of(sc * w[e]);
      whi[g][kk] = hi;
    }
  }

  float h = 0.0f;                          // h[batch=quad][j], fp32 carry
  // A[m=nn][k]: rows nn&3==0 real (batch row nn>>2 at LDS row nn>>2).
  // Banks on read: (16*(row&1) + 4*quad) -> 2-way, free (R12-measured).
  const bool rlane = ((nn & 3) == 0);
  const int a_off  = (nn >> 2) * S_H + quad * 8;   // shorts, + kk*32
  const int w_off  = quad * S_H + j;               // even lanes store b32
  const bool wlane = ((nn & 1) == 0);

  __syncthreads();

  const floatx4 Z = {0.f, 0.f, 0.f, 0.f};
  short8 ah0 = {0,0,0,0,0,0,0,0}, ah1 = ah0, ah2 = ah0, ah3 = ah0;

  auto step = [&](const short* __restrict__ hc, short* __restrict__ nx,
                  float xt) {
    if (rlane) {                           // 16 lanes/wave, 2-way banks
      ah0 = *(const short8*)(hc + a_off);
      ah1 = *(const short8*)(hc + a_off + 32);
      ah2 = *(const short8*)(hc + a_off + 64);
      ah3 = *(const short8*)(hc + a_off + 96);
    }
    // x-terms off the critical chain
    const float wrc = fmaf(xt, wi_rn, c_rn);
    const float wzc = fmaf(xt, wi_zn, c_zn);
    const float u   = fmaf(xt, win2, bin2);

    // gate-major, depth-1 x4: r exits the matrix pipe at slot 4/12 ->
    // sigmoid(r), sigmoid(z) overlap the n-chain drain
    __builtin_amdgcn_s_setprio(1);
    floatx4 ra = MFMA_BF16(ah0, whi[0][0], Z, 0, 0, 0);
    floatx4 rb = MFMA_BF16(ah1, whi[0][1], Z, 0, 0, 0);
    floatx4 rc = MFMA_BF16(ah2, whi[0][2], Z, 0, 0, 0);
    floatx4 rd = MFMA_BF16(ah3, whi[0][3], Z, 0, 0, 0);
    floatx4 za = MFMA_BF16(ah0, whi[1][0], Z, 0, 0, 0);
    floatx4 zb = MFMA_BF16(ah1, whi[1][1], Z, 0, 0, 0);
    floatx4 zc = MFMA_BF16(ah2, whi[1][2], Z, 0, 0, 0);
    floatx4 zd = MFMA_BF16(ah3, whi[1][3], Z, 0, 0, 0);
    floatx4 na = MFMA_BF16(ah0, whi[2][0], Z, 0, 0, 0);
    floatx4 nb = MFMA_BF16(ah1, whi[2][1], Z, 0, 0, 0);
    floatx4 nc = MFMA_BF16(ah2, whi[2][2], Z, 0, 0, 0);
    floatx4 nd = MFMA_BF16(ah3, whi[2][3], Z, 0, 0, 0);
    __builtin_amdgcn_s_setprio(0);

    // C reg 0 = (batch row quad, column j). Scalar trees, 2 levels.
    const float rs = (ra[0] + rb[0]) + (rc[0] + rd[0]);
    const float zs = (za[0] + zb[0]) + (zc[0] + zd[0]);
    const float rg = __builtin_amdgcn_rcpf(
        1.0f + __builtin_amdgcn_exp2f(rs + wrc));
    const float zg = __builtin_amdgcn_rcpf(
        1.0f + __builtin_amdgcn_exp2f(zs + wzc));
    const float ns = (na[0] + nb[0]) + (nc[0] + nd[0]);
    const float t  = fmaf(rg, ns + bhn2, u);
    const float ng = fmaf(-2.0f, __builtin_amdgcn_rcpf(
        1.0f + __builtin_amdgcn_exp2f(t)), 1.0f);
    h = fmaf(zg, h - ng, ng);              // z*h + (1-z)*n, fp32 carry

    // packed bf16x2 store: DPP quad_perm [1,0,3,2] neighbor + cvt_pk (RNE);
    // even lanes store one dword; banks 2-way (free)
    const float hnb = __int_as_float(
        __builtin_amdgcn_mov_dpp(__float_as_int(h), 0xB1, 0xF, 0xF, true));
    int hp;
    asm("v_cvt_pk_bf16_f32 %0, %1, %2" : "=v"(hp) : "v"(h), "v"(hnb));
    if (wlane) *(int*)(nx + w_off) = hp;
  };

  for (int t = 0; t < SEQ_T; t += 2) {
    const float xa = xs[t][quad];
    const float xb = xs[t + 1][quad];
    step(hb[0], hb[1], xa);
    __syncthreads();
    step(hb[1], hb[0], xb);
    __syncthreads();
  }

  // epilogue: logits = h @ Wfc^T + bfc (fp32), 4 rows x 10 outs
  hfin[quad][j] = h;
  __syncthreads();
  if (tid < 40) {
    const int r = tid / 10, o = tid - r * 10;
    float acc = bfc[o];
    #pragma unroll 4
    for (int k = 0; k < HID; ++k)
      acc = fmaf(hfin[r][k], Wfc[o * HID + k], acc);
    out[(size_t)(b0 + r) * 10 + o] = acc;
  }
}

extern "C" void kernel_launch(void* const* d_in, const int* in_sizes, int n_in,
                              void* d_out, int out_size, void* d_ws, size_t ws_size,
                              hipStream_t stream) {
  const float* x   = (const float*)d_in[0];
  const float* Wi  = (const float*)d_in[1];
  const float* bi  = (const float*)d_in[2];
  const float* Wh  = (const float*)d_in[3];
  const float* bh  = (const float*)d_in[4];
  const float* Wfc = (const float*)d_in[5];
  const float* bfc = (const float*)d_in[6];
  hipLaunchKernelGGL(gru_lat_t, dim3(256), dim3(512), 0, stream,
                     x, Wi, bi, Wh, bh, Wfc, bfc, (float*)d_out);
}

// Round 8
// 338.015 us; speedup vs baseline: 1.0370x; 1.0370x over previous
//
#include <hip/hip_runtime.h>

#define SEQ_T 784
#define HID   128
#define S_H   160   // h-plane row stride in shorts (320B): masked reads land
                    // 2-per-bank-window (free, m136); R12-measured 1.19e5 conflicts

typedef __attribute__((ext_vector_type(8))) short  short8;
typedef __attribute__((ext_vector_type(4))) float  floatx4;
typedef __attribute__((ext_vector_type(8))) float  float8;

// bf16 round-to-nearest-even on raw bits (inputs finite)
static __device__ __forceinline__ short bf16_of(float f) {
  union { float f; unsigned u; } v; v.f = f;
  return (short)((v.u + 0x7fffu + ((v.u >> 16) & 1u)) >> 16);
}

#define MFMA_BF16 __builtin_amdgcn_mfma_f32_16x16x32_bf16

// 256 blocks x 4 batch rows (1 block/CU). Step model (R12-R15 measured):
// MFMA-busy 405-410 cyc/step invariant (96 MFMA/block = 3 gates x 24 N-tiles
// x 4 K, M-rows don't enter); serial remainder ~420 (read ~120, trail-wave
// tail ~100, write+barrier ~150). R15 lesson: depth-1/12-dest burst exposed
// 12 MFMA->VALU result hazards, +96 cyc idle -> keep C-in chained (free pipe
// forwarding), few results, read late. R16 = R12 skeleton +
//  - exp2-fold baked into Wh/Wi constants (R15's safe half; absmax 4.88e-4)
//  - chain completion order r(slot 8) -> n(10) -> z(12): rg computed during
//    slots 9-12; ng's 5-op chain (needs rg) starts at 10's drain; zg (3 ops)
//    last -> tail ~50 cyc past last issue
//  - masked 2-way-free reads, packed DPP+cvt_pk b32 store, setprio, x2 unroll
extern "C" __global__ void __launch_bounds__(512, 2)
gru_r16_t(const float* __restrict__ x,    // [1024][784] fp32
          const float* __restrict__ Wi,   // [384]
          const float* __restrict__ bi,   // [384]
          const float* __restrict__ Wh,   // [384][128]
          const float* __restrict__ bh,   // [384]
          const float* __restrict__ Wfc,  // [10][128]
          const float* __restrict__ bfc,  // [10]
          float* __restrict__ out)        // [1024][10] fp32
{
  const int tid  = threadIdx.x;
  const int wv   = tid >> 6;
  const int lane = tid & 63;
  const int quad = lane >> 4;
  const int nn   = lane & 15;
  const int j    = (wv << 4) | nn;   // this lane's hidden column
  const int b0   = blockIdx.x * 4;   // 4 batch rows per block

  __shared__ __align__(16) float xs[SEQ_T][4];     // x fp32, [t][row]
  __shared__ __align__(16) short hb[2][4 * S_H];   // h bf16, 4 rows, dbuf
  __shared__ float hfin[4][HID];

  for (int i = tid; i < 2 * 4 * S_H; i += 512) ((short*)hb)[i] = 0;
  for (int i = tid; i < 4 * SEQ_T; i += 512) {
    const int r = i / SEQ_T;
    const int t = i - r * SEQ_T;
    xs[t][r] = x[(size_t)(b0 + r) * SEQ_T + t];
  }

  const float L2E  = 1.4426950408889634f;
  const float TL2E = 2.0f * L2E;

  // x-side constants, pre-scaled to match the weight scaling below:
  // sigmoid(p) = rcp(1 + exp2(-L2E*p));  tanh(q) = 1 - 2*rcp(1 + exp2(2*L2E*q))
  const float wi_rn = -Wi[j] * L2E;
  const float c_rn  = -(bi[j] + bh[j]) * L2E;
  const float wi_zn = -Wi[HID + j] * L2E;
  const float c_zn  = -(bi[HID + j] + bh[HID + j]) * L2E;
  const float win2  = Wi[2 * HID + j] * TL2E;
  const float bin2  = bi[2 * HID + j] * TL2E;
  const float bhn2  = bh[2 * HID + j] * TL2E;

  // Wh B-fragments, bf16, exp2 fold baked in: r,z scaled by -L2E, n by +2*L2E.
  // Lane (quad,nn): B[k = kk*32 + quad*8 + e][n = nn] = scale*Wh[g*HID+j][k]
  short8 whi[3][4];
  #pragma unroll
  for (int g = 0; g < 3; ++g) {
    const float sc = (g == 2) ? TL2E : -L2E;
    const float* wrow = Wh + (size_t)(g * HID + j) * HID;
    #pragma unroll
    for (int kk = 0; kk < 4; ++kk) {
      float8 w = *(const float8*)(wrow + kk * 32 + quad * 8);
      short8 hi;
      #pragma unroll
      for (int e = 0; e < 8; ++e) hi[e] = bf16_of(sc * w[e]);
      whi[g][kk] = hi;
    }
  }

  float h = 0.0f;                          // h[batch=quad][j], fp32 carry
  // A[m=nn][k]: rows nn&3==0 real (batch row nn>>2 at LDS row nn>>2)
  const bool rlane = ((nn & 3) == 0);
  const int a_off  = (nn >> 2) * S_H + quad * 8;   // shorts, + kk*32
  const int w_off  = quad * S_H + j;               // even lanes store b32
  const bool wlane = ((nn & 1) == 0);

  __syncthreads();

  const floatx4 Z = {0.f, 0.f, 0.f, 0.f};
  short8 ah0 = {0,0,0,0,0,0,0,0}, ah1 = ah0, ah2 = ah0, ah3 = ah0;

  auto step = [&](const short* __restrict__ hc, short* __restrict__ nx,
                  float xt) {
    if (rlane) {                           // 16 lanes/wave, 2-way banks
      ah0 = *(const short8*)(hc + a_off);
      ah1 = *(const short8*)(hc + a_off + 32);
      ah2 = *(const short8*)(hc + a_off + 64);
      ah3 = *(const short8*)(hc + a_off + 96);
    }
    // x-terms off the critical chain
    const float wrc = fmaf(xt, wi_rn, c_rn);
    const float wzc = fmaf(xt, wi_zn, c_zn);
    const float u   = fmaf(xt, win2, bin2);

    // depth-2 chains, completion order r(8) n(10) z(12); C-in accumulation
    // stays in the matrix pipe (free forwarding), 6 results read by VALU
    __builtin_amdgcn_s_setprio(1);
    floatx4 r0 = MFMA_BF16(ah0, whi[0][0], Z, 0, 0, 0);
    floatx4 r1 = MFMA_BF16(ah1, whi[0][1], Z, 0, 0, 0);
    floatx4 n0 = MFMA_BF16(ah0, whi[2][0], Z, 0, 0, 0);
    floatx4 n1 = MFMA_BF16(ah1, whi[2][1], Z, 0, 0, 0);
    floatx4 z0 = MFMA_BF16(ah0, whi[1][0], Z, 0, 0, 0);
    floatx4 z1 = MFMA_BF16(ah1, whi[1][1], Z, 0, 0, 0);
    r0 = MFMA_BF16(ah2, whi[0][2], r0, 0, 0, 0);
    r1 = MFMA_BF16(ah3, whi[0][3], r1, 0, 0, 0);
    n0 = MFMA_BF16(ah2, whi[2][2], n0, 0, 0, 0);
    n1 = MFMA_BF16(ah3, whi[2][3], n1, 0, 0, 0);
    z0 = MFMA_BF16(ah2, whi[1][2], z0, 0, 0, 0);
    z1 = MFMA_BF16(ah3, whi[1][3], z1, 0, 0, 0);
    __builtin_amdgcn_s_setprio(0);

    // C reg 0 = (batch row quad, column j).
    const float rg = __builtin_amdgcn_rcpf(
        1.0f + __builtin_amdgcn_exp2f((r0[0] + r1[0]) + wrc));
    const float t  = fmaf(rg, (n0[0] + n1[0]) + bhn2, u);
    const float ng = fmaf(-2.0f, __builtin_amdgcn_rcpf(
        1.0f + __builtin_amdgcn_exp2f(t)), 1.0f);
    const float zg = __builtin_amdgcn_rcpf(
        1.0f + __builtin_amdgcn_exp2f((z0[0] + z1[0]) + wzc));
    h = fmaf(zg, h - ng, ng);              // z*h + (1-z)*n, fp32 carry

    // packed bf16x2 store: DPP quad_perm [1,0,3,2] neighbor + cvt_pk (RNE);
    // even lanes store one dword; banks 2-way (free)
    const float hnb = __int_as_float(
        __builtin_amdgcn_mov_dpp(__float_as_int(h), 0xB1, 0xF, 0xF, true));
    int hp;
    asm("v_cvt_pk_bf16_f32 %0, %1, %2" : "=v"(hp) : "v"(h), "v"(hnb));
    if (wlane) *(int*)(nx + w_off) = hp;
  };

  for (int t = 0; t < SEQ_T; t += 2) {
    const float xa = xs[t][quad];
    const float xb = xs[t + 1][quad];
    step(hb[0], hb[1], xa);
    __syncthreads();
    step(hb[1], hb[0], xb);
    __syncthreads();
  }

  // epilogue: logits = h @ Wfc^T + bfc (fp32), 4 rows x 10 outs
  hfin[quad][j] = h;
  __syncthreads();
  if (tid < 40) {
    const int r = tid / 10, o = tid - r * 10;
    float acc = bfc[o];
    #pragma unroll 4
    for (int k = 0; k < HID; ++k)
      acc = fmaf(hfin[r][k], Wfc[o * HID + k], acc);
    out[(size_t)(b0 + r) * 10 + o] = acc;
  }
}

extern "C" void kernel_launch(void* const* d_in, const int* in_sizes, int n_in,
                              void* d_out, int out_size, void* d_ws, size_t ws_size,
                              hipStream_t stream) {
  const float* x   = (const float*)d_in[0];
  const float* Wi  = (const float*)d_in[1];
  const float* bi  = (const float*)d_in[2];
  const float* Wh  = (const float*)d_in[3];
  const float* bh  = (const float*)d_in[4];
  const float* Wfc = (const float*)d_in[5];
  const float* bfc = (const float*)d_in[6];
  hipLaunchKernelGGL(gru_r16_t, dim3(256), dim3(512), 0, stream,
                     x, Wi, bi, Wh, bh, Wfc, bfc, (float*)d_out);
}